// Round 5
// baseline (255.944 us; speedup 1.0000x reference)
//
#include <hip/hip_runtime.h>
#include <hip/hip_bf16.h>
#include <cmath>
#include <cstdint>

// CrossAttention: out = softmax((x Wq)(ctx Wk)^T * 1/8) (ctx Wv) Wo + bo
// b=2, n=m=4096, H=8, D=64, qdim=1024, cdim=768, inner=512.
// Round 13:
//  - V^T projection is now its OWN GEMM with swapped operand roles:
//    vt[c][m] = sum_k WvT[c][k] * ctx[m][k]  (A=WvT M'=512, B=ctxb N'=8192).
//    Output rows contiguous in m -> coalesced 32B store groups. This replaces
//    the round-12 per-element 8KB-stride scatter (~16-32x write amplification,
//    the ~40us non-attn anomaly).
//  - Q, K, V^T all in ONE 768-block launch (3 blocks/CU), 1-D decoded grid.
//  - attn: QK^T accumulator initialized via loop-invariant zero f32x16 as
//    MFMA C-in (kills 16 v_mov per tile per wave).

using bf16_t = __hip_bfloat16;
typedef __bf16 bf16x8 __attribute__((ext_vector_type(8)));
typedef float  f32x4  __attribute__((ext_vector_type(4)));
typedef float  f32x16 __attribute__((ext_vector_type(16)));

static constexpr int BATCH = 2;
static constexpr int NQ    = 4096;
static constexpr int NKV   = 4096;
static constexpr int NH    = 8;
static constexpr int DH    = 64;
static constexpr int INNER = NH * DH;   // 512
static constexpr int QDIM  = 1024;
static constexpr int CDIM  = 768;
// Q is pre-scaled by SCALE*log2(e) so softmax uses exp2 directly.
static constexpr float QSCALE = 0.125f * 1.4426950408889634f;  // 0.18033688

#define MFMA_BF16(a, b, c) __builtin_amdgcn_mfma_f32_16x16x32_bf16((a), (b), (c), 0, 0, 0)
#define MFMA32_BF16(a, b, c) __builtin_amdgcn_mfma_f32_32x32x16_bf16((a), (b), (c), 0, 0, 0)

__device__ __forceinline__ float fast_exp2(float x) {
  return __builtin_amdgcn_exp2f(x);
}

// async global->LDS, 16B per lane; LDS dest is wave-uniform base + lane*16 (HW).
__device__ __forceinline__ void gload16(const bf16_t* g, bf16_t* l) {
  __builtin_amdgcn_global_load_lds((__attribute__((address_space(1))) void*)(g),
                                   (__attribute__((address_space(3))) void*)(l),
                                   16, 0, 0);
}

// pack two f32 -> u32 of 2 bf16 (compiler emits v_cvt_pk_bf16_f32)
__device__ __forceinline__ uint32_t pk2(float lo, float hi) {
  __hip_bfloat16 a = __float2bfloat16(lo), b = __float2bfloat16(hi);
  union { unsigned short s[2]; uint32_t u; } x;
  x.s[0] = *(unsigned short*)&a;
  x.s[1] = *(unsigned short*)&b;
  return x.u;
}

// v_permlane32_swap_b32: a' = {a_lo, b_lo(from lane-32)}, b' = {a_hi(to lane+32), b_hi}
__device__ __forceinline__ void pl32swap(uint32_t& a, uint32_t& b) {
  asm volatile("v_permlane32_swap_b32 %0, %1" : "+v"(a), "+v"(b));
}

__device__ __forceinline__ bf16x8 frag4(uint32_t w0, uint32_t w1, uint32_t w2, uint32_t w3) {
  union { uint32_t w[4]; bf16x8 f; } u;
  u.w[0] = w0; u.w[1] = w1; u.w[2] = w2; u.w[3] = w3;
  return u.f;
}

// ---------- fused f32 -> bf16 cast of x and ctx ----------
__global__ __launch_bounds__(256) void cast2_kernel(const float* __restrict__ x,
                                                    bf16_t* __restrict__ xb, int xn8,
                                                    const float* __restrict__ c,
                                                    bf16_t* __restrict__ cb, int cn8) {
  int id = blockIdx.x * 256 + threadIdx.x;
  const float* in;
  bf16_t* out;
  if (id < xn8) {
    in = x; out = xb;
  } else {
    id -= xn8;
    if (id >= cn8) return;
    in = c; out = cb;
  }
  float4 a = ((const float4*)in)[2 * id];
  float4 b = ((const float4*)in)[2 * id + 1];
  bf16_t t[8] = {__float2bfloat16(a.x), __float2bfloat16(a.y), __float2bfloat16(a.z),
                 __float2bfloat16(a.w), __float2bfloat16(b.x), __float2bfloat16(b.y),
                 __float2bfloat16(b.z), __float2bfloat16(b.w)};
  ((uint4*)out)[id] = *(const uint4*)t;
}

// ---------- fused weight transpose: 4 matrices, W[K][N] f32 -> WT[N][K] bf16 ----------
__global__ __launch_bounds__(256) void wtrans4_kernel(const float* __restrict__ Wq,
                                                      const float* __restrict__ Wk,
                                                      const float* __restrict__ Wv,
                                                      const float* __restrict__ Wo,
                                                      bf16_t* __restrict__ WqT,
                                                      bf16_t* __restrict__ WkvT,
                                                      bf16_t* __restrict__ WoT) {
  __shared__ float tile[32][33];
  const float* W;
  bf16_t* WT;
  int K, N;
  switch (blockIdx.z) {
    case 0: W = Wq; WT = WqT; K = QDIM; N = INNER; break;
    case 1: W = Wk; WT = WkvT; K = CDIM; N = INNER; break;
    case 2: W = Wv; WT = WkvT + (size_t)INNER * CDIM; K = CDIM; N = INNER; break;
    default: W = Wo; WT = WoT; K = INNER; N = QDIM; break;
  }
  const int bn = blockIdx.x * 32, bk = blockIdx.y * 32;
  if (bn >= N || bk >= K) return;
  const int tx = threadIdx.x & 31, ty = threadIdx.x >> 5;  // ty 0..7
  for (int yy = ty; yy < 32; yy += 8)
    tile[yy][tx] = W[(size_t)(bk + yy) * N + bn + tx];
  __syncthreads();
  for (int yy = ty; yy < 32; yy += 8)
    WT[(size_t)(bn + yy) * K + bk + tx] = __float2bfloat16(tile[tx][yy]);
}

// ---------- 128x128 MFMA GEMM core, triple-buffer + counted vmcnt ----------
// Per iter: wait vmcnt(4) [stage(t) done, stage(t+1) in flight]; s_barrier;
// issue stage(t+2); ds_read fragments (swizzled); 16 MFMA/wave.
// Swizzle (rule #21): LDS stays linear; the 16B column-granule of the GLOBAL
// source is XOR'd with s(row)=(row>>1)&3, and reads XOR the same way.
__device__ __forceinline__ void gemm128_core(const bf16_t* __restrict__ A,
                                             const bf16_t* __restrict__ WT, int K,
                                             int m0, int n0, int tid,
                                             f32x4 (&acc)[4][4],
                                             bf16_t (*As)[128][32],
                                             bf16_t (*Bs)[128][32]) {
  const int lane = tid & 63, wave = tid >> 6;
  const int lane15 = lane & 15, quad = lane >> 4;
  const int wm = (wave >> 1) * 64, wn = (wave & 1) * 64;
  const int srow = tid >> 2;                                // 0..63 (+64 chunk)
  const int scol = ((tid & 3) ^ ((srow >> 1) & 3)) * 8;     // inverse-swizzled src
  const bf16_t* aptr = A + (size_t)(m0 + srow) * K + scol;
  const bf16_t* bptr = WT + (size_t)(n0 + srow) * K + scol;
  bf16_t* const ab = &As[0][wave * 16][0];   // wave-uniform base (+lane*16 by HW)
  bf16_t* const bb = &Bs[0][wave * 16][0];
  constexpr int BUF = 128 * 32;

  auto stage = [&](int t) {
    const int c = (t % 3) * BUF;
    const bf16_t* as = aptr + t * 32;
    const bf16_t* bs = bptr + t * 32;
    gload16(as, ab + c);                                   // A rows [0,64)
    gload16(as + (size_t)64 * K, ab + c + 64 * 32);        // A rows [64,128)
    gload16(bs, bb + c);
    gload16(bs + (size_t)64 * K, bb + c + 64 * 32);
  };

  const int T = K / 32;
  stage(0);
  stage(1);
  for (int t = 0; t < T; ++t) {
    const int cur = t % 3;
    if (t < T - 1) {
      asm volatile("s_waitcnt vmcnt(4)" ::: "memory");  // buf[t] done, buf[t+1] flying
    } else {
      asm volatile("s_waitcnt vmcnt(0)" ::: "memory");  // tail
    }
    asm volatile("s_barrier" ::: "memory");
    if (t + 2 < T) stage(t + 2);                        // never drained this iter
    bf16x8 af[4], bfr[4];
#pragma unroll
    for (int i = 0; i < 4; ++i) {
      const int row = wm + i * 16 + lane15;
      af[i] = *reinterpret_cast<const bf16x8*>(
          &As[cur][0][0] + row * 32 + ((quad * 8) ^ (((row >> 1) & 3) * 8)));
    }
#pragma unroll
    for (int j = 0; j < 4; ++j) {
      const int row = wn + j * 16 + lane15;
      bfr[j] = *reinterpret_cast<const bf16x8*>(
          &Bs[cur][0][0] + row * 32 + ((quad * 8) ^ (((row >> 1) & 3) * 8)));
    }
#pragma unroll
    for (int i = 0; i < 4; ++i)
#pragma unroll
      for (int j = 0; j < 4; ++j) acc[i][j] = MFMA_BF16(af[i], bfr[j], acc[i][j]);
  }
}

// ---------- unified projection GEMM: Q, K, V^T in one 768-block launch ----------
// bid <  256: Q  = xb   @ WqT^T          -> qob  (bf16, *QSCALE)   [M=8192 N=512 K=1024]
// bid <  512: K  = ctxb @ WkT^T          -> kb   (bf16)            [M=8192 N=512 K=768]
// bid >= 512: VT = WvT  @ ctxb^T         -> vtb  (bf16, coalesced) [M'=512 N'=8192 K=768]
__global__ __launch_bounds__(256, 3) void proj_gemm_kernel(const bf16_t* __restrict__ xb,
                                                           const bf16_t* __restrict__ ctxb,
                                                           const bf16_t* __restrict__ WqT,
                                                           const bf16_t* __restrict__ WkvT,
                                                           bf16_t* __restrict__ qob,
                                                           bf16_t* __restrict__ kb,
                                                           bf16_t* __restrict__ vtb) {
  __shared__ __align__(16) bf16_t As[3][128][32];   // 24 KB
  __shared__ __align__(16) bf16_t Bs[3][128][32];   // 24 KB
  const int tid = threadIdx.x;
  const int bid = blockIdx.x;
  const bf16_t *A, *WT;
  int K, m0, n0, mode;
  if (bid < 256) {
    mode = 0; A = xb; WT = WqT; K = QDIM;
    m0 = (bid >> 2) * 128; n0 = (bid & 3) * 128;
  } else if (bid < 512) {
    const int i = bid - 256;
    mode = 1; A = ctxb; WT = WkvT; K = CDIM;      // WkvT rows [0,512) = Wk^T
    m0 = (i >> 2) * 128; n0 = (i & 3) * 128;
  } else {
    const int i = bid - 512;
    mode = 2; A = WkvT + (size_t)INNER * CDIM;     // Wv^T [c][k]
    WT = ctxb; K = CDIM;
    m0 = (i & 3) * 128;                            // c-tile (512 rows)
    n0 = (i >> 2) * 128;                           // m-tile (8192 cols)
  }

  const f32x4 vzero = {0.f, 0.f, 0.f, 0.f};
  f32x4 acc[4][4];
  for (int i = 0; i < 4; ++i)
    for (int j = 0; j < 4; ++j) acc[i][j] = vzero;

  gemm128_core(A, WT, K, m0, n0, tid, acc, As, Bs);

  // epilogue: C/D layout col=lane&15, row=quad*4+reg  [verified m89/m91]
  const int lane = tid & 63, wave = tid >> 6;
  const int lane15 = lane & 15, quad = lane >> 4;
  const int wm = (wave >> 1) * 64, wn = (wave & 1) * 64;
  for (int i = 0; i < 4; ++i) {
    int gm = m0 + wm + i * 16 + quad * 4;
    for (int j = 0; j < 4; ++j) {
      int gn = n0 + wn + j * 16 + lane15;
      for (int r = 0; r < 4; ++r) {
        float v = acc[i][j][r];
        if (mode == 0) {
          qob[(size_t)(gm + r) * INNER + gn] = __float2bfloat16(v * QSCALE);
        } else if (mode == 1) {
          kb[(size_t)(gm + r) * INNER + gn] = __float2bfloat16(v);
        } else {
          // vt[b][c][mi]: b = gn>>12, mi = gn&4095, c = gm+r; 16 lane15-consec
          // mi values -> 32B contiguous store group (coalesced).
          vtb[((size_t)(gn >> 12) * INNER + (gm + r)) * (size_t)NKV + (gn & 4095)] =
              __float2bfloat16(v);
        }
      }
    }
  }
}

// ---------- output projection: C[M][1024] f32 = O @ WoT^T + bo, 512 blocks ----------
__global__ __launch_bounds__(256, 3) void out_gemm_kernel(const bf16_t* __restrict__ A,
                                                          const bf16_t* __restrict__ WT,
                                                          float* __restrict__ C,
                                                          const float* __restrict__ bias) {
  __shared__ __align__(16) bf16_t As[3][128][32];
  __shared__ __align__(16) bf16_t Bs[3][128][32];
  const int tid = threadIdx.x;
  const int m0 = blockIdx.x * 128, n0 = blockIdx.y * 128;
  constexpr int K = INNER, N = QDIM;

  const f32x4 vzero = {0.f, 0.f, 0.f, 0.f};
  f32x4 acc[4][4];
  for (int i = 0; i < 4; ++i)
    for (int j = 0; j < 4; ++j) acc[i][j] = vzero;

  gemm128_core(A, WT, K, m0, n0, tid, acc, As, Bs);

  const int lane = tid & 63, wave = tid >> 6;
  const int lane15 = lane & 15, quad = lane >> 4;
  const int wm = (wave >> 1) * 64, wn = (wave & 1) * 64;
  float bv[4];
  for (int j = 0; j < 4; ++j) bv[j] = bias[n0 + wn + j * 16 + lane15];
  for (int i = 0; i < 4; ++i) {
    int gm = m0 + wm + i * 16 + quad * 4;
    for (int j = 0; j < 4; ++j) {
      int gn = n0 + wn + j * 16 + lane15;
      for (int r = 0; r < 4; ++r)
        C[(size_t)(gm + r) * N + gn] = acc[i][j][r] + bv[j];
    }
  }
}

// ---------- flash attention: one (b, h, 128-row Q tile) per block ----------
// 512 threads = 8 waves = 4 q-groups (32 rows each) x 2 kv-halves (32 kv of
// each 64-kv tile). 32x32x16 MFMA throughout.
//   S^T = K Q^T: A=K-frag (m=kv), B=Q-frag (n=q) -> C/D col=lane&31 = q,
//   row = (reg&3)+8*(reg>>2)+4*hi = kv  [HW-verified m74/m101].
// P redistribution IN REGISTER: cvt_pk pairs -> v_permlane32_swap_b32 swaps
// the hi/lo-lane kv halves into PV A-operand order (k = 8*hi + j). No P LDS.
// l via ones-MFMA (acc_l rows == acc_o rows). kv-half partials combined via
// LDS epilogue. K/V double-buffered chunk staging (1 KB contiguous chunks,
// conflict-free), register prefetch, ONE barrier per tile.
__global__ __launch_bounds__(512, 4) void attn_kernel(const bf16_t* Qg /*[b][m][c]*/,
                                                      const bf16_t* __restrict__ Kg /*[b][m][c]*/,
                                                      const bf16_t* __restrict__ Vtg /*[b][c][m]*/,
                                                      bf16_t* Og /*[b][m][c], may alias Qg*/) {
  // staging: 16 chunks of 1 KB per buffer half (K: [v-half][kc], V: [v-half][dt][kb])
  __shared__ __align__(16) char smem[33792];
  auto KsF = (bf16_t(*)[8][512])smem;              // [2][8][512]  16 KB
  auto VtF = (bf16_t(*)[8][512])(smem + 16384);    // [2][8][512]  16 KB
  float* scrO = (float*)smem;                      // epilogue partials (32 KB)
  float* scrL = (float*)(smem + 32768);            // epilogue l partials

  const int tid = threadIdx.x;
  const int lane = tid & 63, wave = tid >> 6;      // wave 0..7
  const int lane31 = lane & 31, hi = lane >> 5;
  const int qg = wave >> 1;                        // q-group 0..3 (32 rows each)
  const int v  = wave & 1;                         // kv-half 0/1
  const int q0 = blockIdx.x * 128;
  const int h = blockIdx.y;
  const int b = blockIdx.z;

  const size_t qbase  = ((size_t)b * NQ + q0) * INNER + h * DH;
  const size_t kbase  = ((size_t)b * NKV) * INNER + h * DH;
  const size_t vtbase = ((size_t)(b * NH + h) * DH) * NKV;

  // Q fragments (B-operand): n=q=lane31, k = kc*16 + hi*8 + j  (pre-scaled)
  bf16x8 qf[4];
#pragma unroll
  for (int kc = 0; kc < 4; ++kc)
    qf[kc] = *reinterpret_cast<const bf16x8*>(
        Qg + qbase + (size_t)(qg * 32 + lane31) * INNER + kc * 16 + hi * 8);

  bf16x8 ones;
#pragma unroll
  for (int i = 0; i < 8; ++i) ones[i] = (__bf16)1.0f;

  f32x16 z16;  // loop-invariant zeros: C-in for the first QK^T MFMA (no per-
#pragma unroll  // iter 16x v_mov zero-init of st)
  for (int i = 0; i < 16; ++i) z16[i] = 0.f;

  f32x16 acc_o[2];  // [dt]: O[q=row(reg,hi)][d = dt*32+lane31]
  f32x16 acc_l;     // l[q=row(reg,hi)] replicated over cols
  for (int i = 0; i < 16; ++i) { acc_o[0][i] = 0.f; acc_o[1][i] = 0.f; acc_l[i] = 0.f; }

  // staging: wave w stages K-chunk w and V-chunk w (1 KB = 64 lanes x 16B)
  //   K chunk w: [kv = kv0 + (w>>2)*32 + lane31][d = (w&3)*16 + hi*8 ..+7]
  //   V chunk w: Vt[d = ((w>>1)&1)*32 + lane31][kv = kv0 + (w>>2)*32 + (w&1)*16 + hi*8 ..+7]
  const int skv = (wave >> 2) * 32, skc = (wave & 3) * 16;
  const int sdt = ((wave >> 1) & 1) * 32, skb = (wave & 1) * 16;
  auto kaddr = [&](int kv0) {
    return Kg + kbase + (size_t)(kv0 + skv + lane31) * INNER + skc + hi * 8;
  };
  auto vaddr = [&](int kv0) {
    return Vtg + vtbase + (size_t)(sdt + lane31) * NKV + kv0 + skv + skb + hi * 8;
  };
  uint4 kr = *(const uint4*)kaddr(0);
  uint4 vr = *(const uint4*)vaddr(0);

  constexpr int T = NKV / 64;
  for (int t = 0; t < T; ++t) {
    const int cur = t & 1;
    *(uint4*)&KsF[cur][wave][lane * 8] = kr;  // compiler waits vmcnt for kr/vr here
    *(uint4*)&VtF[cur][wave][lane * 8] = vr;
    __syncthreads();  // publish buf[cur]; no outstanding vmcnt (kr/vr consumed)

    // prefetch next K/V tile: in flight across this whole iteration
    if (t + 1 < T) {
      kr = *(const uint4*)kaddr((t + 1) * 64);
      vr = *(const uint4*)vaddr((t + 1) * 64);
    }

    // S^T = K Q^T over this wave's 32-kv half: 4 MFMAs (kc chunks of 16)
    __builtin_amdgcn_s_setprio(1);
    bf16x8 kf0 = *reinterpret_cast<const bf16x8*>(&KsF[cur][v * 4 + 0][lane * 8]);
    f32x16 st = MFMA32_BF16(kf0, qf[0], z16);
#pragma unroll
    for (int kc = 1; kc < 4; ++kc) {
      bf16x8 kf = *reinterpret_cast<const bf16x8*>(&KsF[cur][v * 4 + kc][lane * 8]);
      st = MFMA32_BF16(kf, qf[kc], st);
    }
    __builtin_amdgcn_s_setprio(0);

    // softmax: p = exp2(s); lane holds q=lane31, kv = (reg&3)+8*(reg>>2)+4*hi.
    // pack kv-consecutive pairs: c[2s] = kv(8s+4hi+0,1), c[2s+1] = kv(+2,3)
    uint32_t c0 = pk2(fast_exp2(st[0]),  fast_exp2(st[1]));
    uint32_t c1 = pk2(fast_exp2(st[2]),  fast_exp2(st[3]));
    uint32_t c2 = pk2(fast_exp2(st[4]),  fast_exp2(st[5]));
    uint32_t c3 = pk2(fast_exp2(st[6]),  fast_exp2(st[7]));
    uint32_t c4 = pk2(fast_exp2(st[8]),  fast_exp2(st[9]));
    uint32_t c5 = pk2(fast_exp2(st[10]), fast_exp2(st[11]));
    uint32_t c6 = pk2(fast_exp2(st[12]), fast_exp2(st[13]));
    uint32_t c7 = pk2(fast_exp2(st[14]), fast_exp2(st[15]));
    // A-frag kb=0 covers kv = 8*hi + 0..7; kb=1 covers 16 + 8*hi + 0..7.
    // swap(a,b): a' = {a_lo, b_lo^}, b' = {a_hi^, b_hi}  -> w0/w2 of the frag.
    pl32swap(c0, c2);  // frag0: w0=c0, w2=c2
    pl32swap(c1, c3);  // frag0: w1=c1, w3=c3
    pl32swap(c4, c6);  // frag1: w0=c4, w2=c6
    pl32swap(c5, c7);  // frag1: w1=c5, w3=c7
    bf16x8 pf0 = frag4(c0, c1, c2, c3);
    bf16x8 pf1 = frag4(c4, c5, c6, c7);

    // O += P V ; l += P 1   (V chunks: [v][dt][kb], B-operand layout)
    __builtin_amdgcn_s_setprio(1);
    acc_l = MFMA32_BF16(pf0, ones, acc_l);
    acc_l = MFMA32_BF16(pf1, ones, acc_l);
#pragma unroll
    for (int dt = 0; dt < 2; ++dt) {
      bf16x8 vf0 = *reinterpret_cast<const bf16x8*>(&VtF[cur][v * 4 + dt * 2 + 0][lane * 8]);
      bf16x8 vf1 = *reinterpret_cast<const bf16x8*>(&VtF[cur][v * 4 + dt * 2 + 1][lane * 8]);
      acc_o[dt] = MFMA32_BF16(pf0, vf0, acc_o[dt]);
      acc_o[dt] = MFMA32_BF16(pf1, vf1, acc_o[dt]);
    }
    __builtin_amdgcn_s_setprio(0);
  }

  // epilogue: combine kv-half partials (wave v=1 -> LDS -> wave v=0)
  __syncthreads();  // all waves done reading staging buffers
  if (v == 1) {
#pragma unroll
    for (int dt = 0; dt < 2; ++dt)
      for (int r = 0; r < 16; ++r)
        scrO[((qg * 2 + dt) * 16 + r) * 64 + lane] = acc_o[dt][r];
    if (lane31 == 0)
      for (int r = 0; r < 16; ++r) scrL[(qg * 2 + hi) * 16 + r] = acc_l[r];
  }
  __syncthreads();
  if (v == 0) {
    for (int r = 0; r < 16; ++r) {
      float lt = acc_l[r] + scrL[(qg * 2 + hi) * 16 + r];
      float inv = 1.f / lt;
      int qrow = qg * 32 + (r & 3) + 8 * (r >> 2) + 4 * hi;
      for (int dt = 0; dt < 2; ++dt) {
        float o = acc_o[dt][r] + scrO[((qg * 2 + dt) * 16 + r) * 64 + lane];
        Og[qbase + (size_t)qrow * INNER + dt * 32 + lane31] = __float2bfloat16(o * inv);
      }
    }
  }
}

extern "C" void kernel_launch(void* const* d_in, const int* in_sizes, int n_in,
                              void* d_out, int out_size, void* d_ws, size_t ws_size,
                              hipStream_t stream) {
  (void)in_sizes; (void)n_in; (void)out_size; (void)ws_size;
  const float* x   = (const float*)d_in[0];  // [2][4096][1024]
  const float* ctx = (const float*)d_in[1];  // [2][4096][768]
  const float* Wq  = (const float*)d_in[2];  // [1024][512]
  const float* Wk  = (const float*)d_in[3];  // [768][512]
  const float* Wv  = (const float*)d_in[4];  // [768][512]
  const float* Wo  = (const float*)d_in[5];  // [512][1024]
  const float* bo  = (const float*)d_in[6];  // [1024]
  float* out = (float*)d_out;                // [2][4096][1024], 33.5 MB

  // workspace layout (~28.8 MB)
  char* ws = (char*)d_ws;
  size_t off = 0;
  auto take = [&](size_t nelem) { bf16_t* p = (bf16_t*)(ws + off); off += nelem * 2; return p; };
  bf16_t* WqT  = take((size_t)INNER * QDIM);        // [512][1024]
  bf16_t* WkvT = take((size_t)(2 * INNER) * CDIM);  // [1024][768]: Wk^T then Wv^T
  bf16_t* WoT  = take((size_t)QDIM * INNER);        // [1024][512]
  bf16_t* qob  = take((size_t)BATCH * NQ * INNER);  // Q (pre-scaled), later O
  bf16_t* kb   = take((size_t)BATCH * NKV * INNER);
  bf16_t* vtb  = take((size_t)BATCH * INNER * NKV); // V transposed [b][c][m]

  // bf16 copies of x/ctx live in d_out (dead until the final GEMM writes it):
  // xb 16.8 MB + ctxb 12.6 MB = 29.4 MB <= 33.5 MB.
  bf16_t* xb   = (bf16_t*)d_out;
  bf16_t* ctxb = xb + (size_t)BATCH * NQ * QDIM;

  const int M = BATCH * NQ;  // 8192
  const int xN8 = BATCH * NQ * QDIM / 8, cN8 = BATCH * NKV * CDIM / 8;

  cast2_kernel<<<(xN8 + cN8 + 255) / 256, 256, 0, stream>>>(x, xb, xN8, ctx, ctxb, cN8);
  wtrans4_kernel<<<dim3(32, 32, 4), 256, 0, stream>>>(Wq, Wk, Wv, Wo, WqT, WkvT, WoT);

  // unified Q / K / V^T projections: 768 blocks (~3/CU at 48 KB LDS)
  proj_gemm_kernel<<<768, 256, 0, stream>>>(xb, ctxb, WqT, WkvT, qob, kb, vtb);

  // attention; O overwrites Q in place (each block reads its Q rows before writing O)
  attn_kernel<<<dim3(NQ / 128, NH, BATCH), 512, 0, stream>>>(qob, kb, vtb, qob);

  // output projection + bias (fp32 out): 512 blocks
  out_gemm_kernel<<<dim3(M / 128, QDIM / 128), 256, 0, stream>>>(qob, WoT, out, bo);
}

// Round 6
// 241.616 us; speedup vs baseline: 1.0593x; 1.0593x over previous
//
#include <hip/hip_runtime.h>
#include <hip/hip_bf16.h>
#include <cmath>
#include <cstdint>

// CrossAttention: out = softmax((x Wq)(ctx Wk)^T * 1/8) (ctx Wv) Wo + bo
// b=2, n=m=4096, H=8, D=64, qdim=1024, cdim=768, inner=512.
// Round 14 = Round-3 config (best measured: 240.0us) + locality/launch deltas:
//  - REVERT attn to 4-wave 16x16 structure (87.8us) and proj to merged K+V.
//  - XCD-chunked bijective blockIdx swizzle (T1) on attn/proj/out:
//    same-(h,b) attn blocks (shared 4.2MB K/V) cluster on one XCD's L2
//    (FETCH 69.7MB -> ~30-40MB predicted); proj clusters same-A-panel blocks.
//  - cast2 + wtrans4 fused into ONE prep launch (wtrans hides under cast).

using bf16_t = __hip_bfloat16;
typedef __bf16 bf16x8 __attribute__((ext_vector_type(8)));
typedef float  f32x4  __attribute__((ext_vector_type(4)));

static constexpr int BATCH = 2;
static constexpr int NQ    = 4096;
static constexpr int NKV   = 4096;
static constexpr int NH    = 8;
static constexpr int DH    = 64;
static constexpr int INNER = NH * DH;   // 512
static constexpr int QDIM  = 1024;
static constexpr int CDIM  = 768;
// Q is pre-scaled by SCALE*log2(e) so softmax uses exp2 directly.
static constexpr float QSCALE = 0.125f * 1.4426950408889634f;  // 0.18033688

#define MFMA_BF16(a, b, c) __builtin_amdgcn_mfma_f32_16x16x32_bf16((a), (b), (c), 0, 0, 0)

__device__ __forceinline__ float fast_exp2(float x) {
  return __builtin_amdgcn_exp2f(x);
}

// async global->LDS, 16B per lane; LDS dest is wave-uniform base + lane*16 (HW).
__device__ __forceinline__ void gload16(const bf16_t* g, bf16_t* l) {
  __builtin_amdgcn_global_load_lds((__attribute__((address_space(1))) void*)(g),
                                   (__attribute__((address_space(3))) void*)(l),
                                   16, 0, 0);
}

// ---------- fused prep: f32->bf16 cast of x and ctx + 4 weight transposes ----------
// blocks [0, 7168): cast (x then ctx, 8 f32 -> 8 bf16 per thread)
// blocks [7168, 8960): 32x32 transpose tiles of Wq/Wk/Wv/Wo -> bf16 WT
__global__ __launch_bounds__(256) void prep_kernel(const float* __restrict__ x,
                                                   const float* __restrict__ ctx,
                                                   const float* __restrict__ Wq,
                                                   const float* __restrict__ Wk,
                                                   const float* __restrict__ Wv,
                                                   const float* __restrict__ Wo,
                                                   bf16_t* __restrict__ xb,
                                                   bf16_t* __restrict__ ctxb,
                                                   bf16_t* __restrict__ WqT,
                                                   bf16_t* __restrict__ WkvT,
                                                   bf16_t* __restrict__ WoT) {
  constexpr int XN8 = BATCH * NQ * QDIM / 8;   // 1048576 (4096 blocks)
  constexpr int CN8 = BATCH * NKV * CDIM / 8;  // 786432  (3072 blocks)
  constexpr int CAST_BLK = (XN8 + CN8) / 256;  // 7168
  __shared__ float tile[32][33];
  const int bid = blockIdx.x;
  if (bid < CAST_BLK) {
    int id = bid * 256 + threadIdx.x;
    const float* in;
    bf16_t* out;
    if (id < XN8) {
      in = x; out = xb;
    } else {
      id -= XN8; in = ctx; out = ctxb;
    }
    float4 a = ((const float4*)in)[2 * id];
    float4 b = ((const float4*)in)[2 * id + 1];
    bf16_t t[8] = {__float2bfloat16(a.x), __float2bfloat16(a.y), __float2bfloat16(a.z),
                   __float2bfloat16(a.w), __float2bfloat16(b.x), __float2bfloat16(b.y),
                   __float2bfloat16(b.z), __float2bfloat16(b.w)};
    ((uint4*)out)[id] = *(const uint4*)t;
    return;
  }
  int wb = bid - CAST_BLK;
  const float* W;
  bf16_t* WT;
  int K, N;
  if (wb < 512) {
    W = Wq; WT = WqT; K = QDIM; N = INNER;                            // 32x16 tiles
  } else if (wb < 896) {
    wb -= 512; W = Wk; WT = WkvT; K = CDIM; N = INNER;                // 24x16
  } else if (wb < 1280) {
    wb -= 896; W = Wv; WT = WkvT + (size_t)INNER * CDIM; K = CDIM; N = INNER;  // 24x16
  } else {
    wb -= 1280; W = Wo; WT = WoT; K = INNER; N = QDIM;                // 16x32
  }
  const int bnt = N / 32;
  const int bn = (wb % bnt) * 32, bk = (wb / bnt) * 32;
  const int tx = threadIdx.x & 31, ty = threadIdx.x >> 5;  // ty 0..7
  for (int yy = ty; yy < 32; yy += 8)
    tile[yy][tx] = W[(size_t)(bk + yy) * N + bn + tx];
  __syncthreads();
  for (int yy = ty; yy < 32; yy += 8)
    WT[(size_t)(bn + yy) * K + bk + tx] = __float2bfloat16(tile[tx][yy]);
}

// ---------- 128x128 MFMA GEMM core, triple-buffer + counted vmcnt ----------
// Per iter: wait vmcnt(4) [stage(t) done, stage(t+1) in flight]; s_barrier;
// issue stage(t+2); ds_read fragments (swizzled); 16 MFMA/wave.
// Swizzle (rule #21): LDS stays linear; the 16B column-granule of the GLOBAL
// source is XOR'd with s(row)=(row>>1)&3, and reads XOR the same way.
__device__ __forceinline__ void gemm128_core(const bf16_t* __restrict__ A,
                                             const bf16_t* __restrict__ WT, int K,
                                             int m0, int n0, int tid,
                                             f32x4 (&acc)[4][4],
                                             bf16_t (*As)[128][32],
                                             bf16_t (*Bs)[128][32]) {
  const int lane = tid & 63, wave = tid >> 6;
  const int lane15 = lane & 15, quad = lane >> 4;
  const int wm = (wave >> 1) * 64, wn = (wave & 1) * 64;
  const int srow = tid >> 2;                                // 0..63 (+64 chunk)
  const int scol = ((tid & 3) ^ ((srow >> 1) & 3)) * 8;     // inverse-swizzled src
  const bf16_t* aptr = A + (size_t)(m0 + srow) * K + scol;
  const bf16_t* bptr = WT + (size_t)(n0 + srow) * K + scol;
  bf16_t* const ab = &As[0][wave * 16][0];   // wave-uniform base (+lane*16 by HW)
  bf16_t* const bb = &Bs[0][wave * 16][0];
  constexpr int BUF = 128 * 32;

  auto stage = [&](int t) {
    const int c = (t % 3) * BUF;
    const bf16_t* as = aptr + t * 32;
    const bf16_t* bs = bptr + t * 32;
    gload16(as, ab + c);                                   // A rows [0,64)
    gload16(as + (size_t)64 * K, ab + c + 64 * 32);        // A rows [64,128)
    gload16(bs, bb + c);
    gload16(bs + (size_t)64 * K, bb + c + 64 * 32);        // B rows [64,128)
  };

  const int T = K / 32;
  stage(0);
  stage(1);
  for (int t = 0; t < T; ++t) {
    const int cur = t % 3;
    if (t < T - 1) {
      asm volatile("s_waitcnt vmcnt(4)" ::: "memory");  // buf[t] done, buf[t+1] flying
    } else {
      asm volatile("s_waitcnt vmcnt(0)" ::: "memory");  // tail
    }
    asm volatile("s_barrier" ::: "memory");
    if (t + 2 < T) stage(t + 2);                        // never drained this iter
    bf16x8 af[4], bfr[4];
#pragma unroll
    for (int i = 0; i < 4; ++i) {
      const int row = wm + i * 16 + lane15;
      af[i] = *reinterpret_cast<const bf16x8*>(
          &As[cur][0][0] + row * 32 + ((quad * 8) ^ (((row >> 1) & 3) * 8)));
    }
#pragma unroll
    for (int j = 0; j < 4; ++j) {
      const int row = wn + j * 16 + lane15;
      bfr[j] = *reinterpret_cast<const bf16x8*>(
          &Bs[cur][0][0] + row * 32 + ((quad * 8) ^ (((row >> 1) & 3) * 8)));
    }
#pragma unroll
    for (int i = 0; i < 4; ++i)
#pragma unroll
      for (int j = 0; j < 4; ++j) acc[i][j] = MFMA_BF16(af[i], bfr[j], acc[i][j]);
  }
}

// ---------- merged Q + KV projection: 768 blocks, XCD-chunked swizzle ----------
// virtual vb: bx = vb/12 (m-tile), bsel = vb%12: bsel<4 -> Q n-tile, else KV n-tile.
// XCD chunking puts all 12 bsel of 8 consecutive m-tiles on one XCD: the A
// panels (xb/ctxb rows) are fetched once per XCD instead of 4-8x.
__global__ __launch_bounds__(256, 3) void qkv_gemm_kernel(const bf16_t* __restrict__ xb,
                                                          const bf16_t* __restrict__ ctxb,
                                                          const bf16_t* __restrict__ WqT,
                                                          const bf16_t* __restrict__ WkvT,
                                                          bf16_t* __restrict__ qob,
                                                          bf16_t* __restrict__ kb,
                                                          bf16_t* __restrict__ vtb) {
  __shared__ __align__(16) bf16_t As[3][128][32];   // 24 KB
  __shared__ __align__(16) bf16_t Bs[3][128][32];   // 24 KB
  const int tid = threadIdx.x;
  const int bid = blockIdx.x;                 // 768 = 8 XCDs x 96
  const int vb = (bid & 7) * 96 + (bid >> 3); // bijective (768 % 8 == 0)
  const int bx = vb / 12, bsel = vb % 12;
  const bool isq = bsel < 4;
  const bf16_t* A  = isq ? xb : ctxb;
  const bf16_t* WT = isq ? WqT : WkvT;
  const int K  = isq ? QDIM : CDIM;
  const int m0 = bx * 128;
  const int n0 = (isq ? bsel : bsel - 4) * 128;

  const f32x4 vzero = {0.f, 0.f, 0.f, 0.f};
  f32x4 acc[4][4];
  for (int i = 0; i < 4; ++i)
    for (int j = 0; j < 4; ++j) acc[i][j] = vzero;

  gemm128_core(A, WT, K, m0, n0, tid, acc, As, Bs);

  // epilogue: C/D layout col=lane&15, row=quad*4+reg  [verified m89/m91]
  const int lane = tid & 63, wave = tid >> 6;
  const int lane15 = lane & 15, quad = lane >> 4;
  const int wm = (wave >> 1) * 64, wn = (wave & 1) * 64;
  for (int i = 0; i < 4; ++i) {
    int gm = m0 + wm + i * 16 + quad * 4;
    for (int j = 0; j < 4; ++j) {
      int gn = n0 + wn + j * 16 + lane15;
      for (int r = 0; r < 4; ++r) {
        float v = acc[i][j][r];
        if (isq) {
          qob[(size_t)(gm + r) * INNER + gn] = __float2bfloat16(v * QSCALE);
        } else if (gn < INNER) {
          kb[(size_t)(gm + r) * INNER + gn] = __float2bfloat16(v);
        } else {
          int gmr = gm + r;  // vt[b][c][mi], b = gmr/4096, mi = gmr%4096
          vtb[((size_t)(gmr >> 12) * INNER + (gn - INNER)) * (size_t)NKV +
              (gmr & 4095)] = __float2bfloat16(v);
        }
      }
    }
  }
}

// ---------- output projection: 512 blocks, XCD-chunked swizzle ----------
__global__ __launch_bounds__(256, 3) void out_gemm_kernel(const bf16_t* __restrict__ A,
                                                          const bf16_t* __restrict__ WT,
                                                          float* __restrict__ C,
                                                          const float* __restrict__ bias) {
  __shared__ __align__(16) bf16_t As[3][128][32];
  __shared__ __align__(16) bf16_t Bs[3][128][32];
  const int tid = threadIdx.x;
  const int bid = blockIdx.x;                 // 512 = 8 XCDs x 64
  const int vb = (bid & 7) * 64 + (bid >> 3); // bijective
  const int m0 = (vb >> 3) * 128, n0 = (vb & 7) * 128;  // 8 n-tiles share m-panel
  constexpr int K = INNER, N = QDIM;

  const f32x4 vzero = {0.f, 0.f, 0.f, 0.f};
  f32x4 acc[4][4];
  for (int i = 0; i < 4; ++i)
    for (int j = 0; j < 4; ++j) acc[i][j] = vzero;

  gemm128_core(A, WT, K, m0, n0, tid, acc, As, Bs);

  const int lane = tid & 63, wave = tid >> 6;
  const int lane15 = lane & 15, quad = lane >> 4;
  const int wm = (wave >> 1) * 64, wn = (wave & 1) * 64;
  float bv[4];
  for (int j = 0; j < 4; ++j) bv[j] = bias[n0 + wn + j * 16 + lane15];
  for (int i = 0; i < 4; ++i) {
    int gm = m0 + wm + i * 16 + quad * 4;
    for (int j = 0; j < 4; ++j) {
      int gn = n0 + wn + j * 16 + lane15;
      for (int r = 0; r < 4; ++r)
        C[(size_t)(gm + r) * N + gn] = acc[i][j][r] + bv[j];
    }
  }
}

// ---------- flash attention: one (b, h, 128-row Q tile) per block ----------
// 256 threads = 4 waves x 32 q-rows. Each wave reads the shared 8 KB K-tile
// and 8 KB V-tile once per iter for 2x16 output rows. S^T = K Q^T; packed b64
// Ps writes in A-operand layout (wave-private rows -> lgkmcnt fence, no second
// barrier). K/V register prefetch double-buffered; ONE barrier per tile, never
// draining the prefetch's vmcnt. l via ones-MFMA (acc_l rows == acc_o rows).
// XCD-chunked block swizzle: one XCD handles 2 (h,b) pairs -> K/V L2-local.
__global__ __launch_bounds__(256, 2) void attn_kernel(const bf16_t* Qg /*[b][m][c]*/,
                                                      const bf16_t* __restrict__ Kg /*[b][m][c]*/,
                                                      const bf16_t* __restrict__ Vtg /*[b][c][m]*/,
                                                      bf16_t* Og /*[b][m][c], may alias Qg*/) {
  // fragment-major: chunk c = ks*4+j holds 64 lanes x 8 bf16 (16B/lane)
  __shared__ __align__(16) bf16_t KsF[2][8][512];  // 16 KB
  __shared__ __align__(16) bf16_t VtF[2][8][512];  // 16 KB
  __shared__ __align__(16) bf16_t PsA[128][72];    // 18 KB (pad: stride 144B)

  const int tid = threadIdx.x;
  const int lane = tid & 63, wave = tid >> 6;     // wave 0..3
  const int lane15 = lane & 15, quad = lane >> 4;
  const int wrow = wave * 32;                     // 32 q-rows per wave
  const int bid = blockIdx.x;                     // 512 = 8 XCDs x 64
  const int vb = (bid & 7) * 64 + (bid >> 3);     // bijective (512 % 8 == 0)
  const int qt = vb & 31, hb = vb >> 5;           // qt fastest within (h,b)
  const int h = hb & 7, b = hb >> 3;
  const int q0 = qt * 128;

  const size_t qbase  = ((size_t)b * NQ + q0) * INNER + h * DH;
  const size_t kbase  = ((size_t)b * NKV) * INNER + h * DH;
  const size_t vtbase = ((size_t)(b * NH + h) * DH) * NKV;

  // Q fragments direct from global: layout m=lane15, k=quad*8+j (pre-scaled)
  bf16x8 qf[2][2];  // [ks][qh]
  for (int ks = 0; ks < 2; ++ks)
    for (int qh = 0; qh < 2; ++qh)
      qf[ks][qh] = *reinterpret_cast<const bf16x8*>(
          Qg + qbase + (size_t)(wrow + qh * 16 + lane15) * INNER + ks * 32 + quad * 8);

  bf16x8 ones;
#pragma unroll
  for (int i = 0; i < 8; ++i) ones[i] = (__bf16)1.0f;

  const f32x4 vzero = {0.f, 0.f, 0.f, 0.f};
  f32x4 acc_o[2][4];   // [qh][j]
  f32x4 acc_l[2];      // [qh]
  for (int qh = 0; qh < 2; ++qh) {
    acc_l[qh] = vzero;
    for (int j = 0; j < 4; ++j) acc_o[qh][j] = vzero;
  }

  // wave stages chunks c0 = 2*wave, c1 = 2*wave+1 of K and V; lane's 16B:
  //   K[kv = (c&3)*16+lane15][k = (c>>2)*32+quad*8 ..+7]
  //   Vt[d = (c&3)*16+lane15][kv = kv0+(c>>2)*32+quad*8 ..+7]
  const int c0 = wave * 2, c1 = wave * 2 + 1;
  auto kaddr = [&](int c, int kv0) {
    return Kg + kbase + (size_t)(kv0 + (c & 3) * 16 + lane15) * INNER + (c >> 2) * 32 + quad * 8;
  };
  auto vaddr = [&](int c, int kv0) {
    return Vtg + vtbase + (size_t)((c & 3) * 16 + lane15) * NKV + kv0 + (c >> 2) * 32 + quad * 8;
  };
  uint4 kr0 = *(const uint4*)kaddr(c0, 0), kr1 = *(const uint4*)kaddr(c1, 0);
  uint4 vr0 = *(const uint4*)vaddr(c0, 0), vr1 = *(const uint4*)vaddr(c1, 0);

  constexpr int T = NKV / 64;
  for (int t = 0; t < T; ++t) {
    const int cur = t & 1;
    *(uint4*)&KsF[cur][c0][lane * 8] = kr0;  // compiler waits vmcnt for kr/vr here
    *(uint4*)&KsF[cur][c1][lane * 8] = kr1;
    *(uint4*)&VtF[cur][c0][lane * 8] = vr0;
    *(uint4*)&VtF[cur][c1][lane * 8] = vr1;
    __syncthreads();  // publish buf[cur]; no outstanding vmcnt (kr/vr consumed)

    // prefetch next K/V tile right after the barrier: full-iter latency cover
    if (t + 1 < T) {
      const int kv0n = (t + 1) * 64;
      kr0 = *(const uint4*)kaddr(c0, kv0n);
      kr1 = *(const uint4*)kaddr(c1, kv0n);
      vr0 = *(const uint4*)vaddr(c0, kv0n);
      vr1 = *(const uint4*)vaddr(c1, kv0n);
    }

    // S^T tiles: rows = kv (A = K-frag), cols = q-row (B = Q-frag, 2x16 rows)
    f32x4 acc_st[2][4];  // [qh][j]
#pragma unroll
    for (int qh = 0; qh < 2; ++qh)
      for (int j = 0; j < 4; ++j) acc_st[qh][j] = vzero;
    __builtin_amdgcn_s_setprio(1);
#pragma unroll
    for (int ks = 0; ks < 2; ++ks) {
      bf16x8 kf[4];
#pragma unroll
      for (int j = 0; j < 4; ++j)
        kf[j] = *reinterpret_cast<const bf16x8*>(&KsF[cur][ks * 4 + j][lane * 8]);
#pragma unroll
      for (int qh = 0; qh < 2; ++qh)
#pragma unroll
        for (int j = 0; j < 4; ++j)
          acc_st[qh][j] = MFMA_BF16(kf[j], qf[ks][qh], acc_st[qh][j]);
    }
    __builtin_amdgcn_s_setprio(0);

    // softmax: p = exp2(s); lane holds kv = j*16+quad*4+r for q-row
    // wrow+qh*16+lane15 -> pack 4 kv-consecutive p as one b64 A-layout write
#pragma unroll
    for (int qh = 0; qh < 2; ++qh)
#pragma unroll
      for (int j = 0; j < 4; ++j) {
        bf16_t t4[4];
        for (int r = 0; r < 4; ++r)
          t4[r] = __float2bfloat16(fast_exp2(acc_st[qh][j][r]));
        *(uint2*)&PsA[wrow + qh * 16 + lane15][j * 16 + quad * 4] = *(const uint2*)t4;
      }
    // PsA rows [wrow, wrow+32) are written and read by THIS wave only:
    // LDS-write completion fence is sufficient, and it doesn't touch vmcnt
    // (so the kr/vr prefetch is never drained here).
    asm volatile("s_waitcnt lgkmcnt(0)" ::: "memory");

    // O += P V   (A: PsA[m][kv=quad*8+jj], B: VtF fragment-major)
    // l += P 1   (acc_l row quad*4+r = q-row offset, replicated over lane15)
    __builtin_amdgcn_s_setprio(1);
#pragma unroll
    for (int ks = 0; ks < 2; ++ks) {
      bf16x8 vf[4];
#pragma unroll
      for (int j = 0; j < 4; ++j)
        vf[j] = *reinterpret_cast<const bf16x8*>(&VtF[cur][ks * 4 + j][lane * 8]);
#pragma unroll
      for (int qh = 0; qh < 2; ++qh) {
        bf16x8 pf = *reinterpret_cast<const bf16x8*>(
            &PsA[wrow + qh * 16 + lane15][ks * 32 + quad * 8]);
        acc_l[qh] = MFMA_BF16(pf, ones, acc_l[qh]);
#pragma unroll
        for (int j = 0; j < 4; ++j) acc_o[qh][j] = MFMA_BF16(pf, vf[j], acc_o[qh][j]);
      }
    }
    __builtin_amdgcn_s_setprio(0);
  }

  // acc_l[qh][r] is l for q-row = wrow + qh*16 + quad*4 + r (acc_o's row slot)
  for (int qh = 0; qh < 2; ++qh)
    for (int r = 0; r < 4; ++r) {
      float invr = 1.f / acc_l[qh][r];
      int row = wrow + qh * 16 + quad * 4 + r;
      for (int j = 0; j < 4; ++j)
        Og[qbase + (size_t)row * INNER + j * 16 + lane15] =
            __float2bfloat16(acc_o[qh][j][r] * invr);
    }
}

extern "C" void kernel_launch(void* const* d_in, const int* in_sizes, int n_in,
                              void* d_out, int out_size, void* d_ws, size_t ws_size,
                              hipStream_t stream) {
  (void)in_sizes; (void)n_in; (void)out_size; (void)ws_size;
  const float* x   = (const float*)d_in[0];  // [2][4096][1024]
  const float* ctx = (const float*)d_in[1];  // [2][4096][768]
  const float* Wq  = (const float*)d_in[2];  // [1024][512]
  const float* Wk  = (const float*)d_in[3];  // [768][512]
  const float* Wv  = (const float*)d_in[4];  // [768][512]
  const float* Wo  = (const float*)d_in[5];  // [512][1024]
  const float* bo  = (const float*)d_in[6];  // [1024]
  float* out = (float*)d_out;                // [2][4096][1024], 33.5 MB

  // workspace layout (~28.8 MB)
  char* ws = (char*)d_ws;
  size_t off = 0;
  auto take = [&](size_t nelem) { bf16_t* p = (bf16_t*)(ws + off); off += nelem * 2; return p; };
  bf16_t* WqT  = take((size_t)INNER * QDIM);        // [512][1024]
  bf16_t* WkvT = take((size_t)(2 * INNER) * CDIM);  // [1024][768]: Wk^T then Wv^T
  bf16_t* WoT  = take((size_t)QDIM * INNER);        // [1024][512]
  bf16_t* qob  = take((size_t)BATCH * NQ * INNER);  // Q (pre-scaled), later O
  bf16_t* kb   = take((size_t)BATCH * NKV * INNER);
  bf16_t* vtb  = take((size_t)BATCH * INNER * NKV); // V transposed [b][c][m]

  // bf16 copies of x/ctx live in d_out (dead until the final GEMM writes it):
  // xb 16.8 MB + ctxb 12.6 MB = 29.4 MB <= 33.5 MB.
  bf16_t* xb   = (bf16_t*)d_out;
  bf16_t* ctxb = xb + (size_t)BATCH * NQ * QDIM;

  // fused cast + weight transpose: 7168 cast blocks + 1792 transpose blocks
  prep_kernel<<<8960, 256, 0, stream>>>(x, ctx, Wq, Wk, Wv, Wo, xb, ctxb, WqT, WkvT, WoT);

  // merged Q + KV projections: 768 blocks (~3/CU at 48 KB LDS), XCD-swizzled
  qkv_gemm_kernel<<<768, 256, 0, stream>>>(xb, ctxb, WqT, WkvT, qob, kb, vtb);

  // attention; O overwrites Q in place (each block reads its Q rows before
  // writing O). 512 blocks, XCD-swizzled (2 (h,b) K/V sets per XCD).
  attn_kernel<<<512, 256, 0, stream>>>(qob, kb, vtb, qob);

  // output projection + bias (fp32 out): 512 blocks, XCD-swizzled
  out_gemm_kernel<<<512, 256, 0, stream>>>(qob, WoT, out, bo);
}

// Round 7
// 237.994 us; speedup vs baseline: 1.0754x; 1.0152x over previous
//
#include <hip/hip_runtime.h>
#include <hip/hip_bf16.h>
#include <cmath>
#include <cstdint>

// CrossAttention: out = softmax((x Wq)(ctx Wk)^T * 1/8) (ctx Wv) Wo + bo
// b=2, n=m=4096, H=8, D=64, qdim=1024, cdim=768, inner=512.
// Round 15 = Round-14 config + PsA bank-conflict fix (single change):
//  - PsA [128][72] pad-stride -> [128][64] (128B row stride) with XOR swizzle
//    byte ^= (row&7)<<4 on the column offset, applied on BOTH the uint2 write
//    and the b128 pf read. Old pf reads collapsed 64 lanes into 8 groups of 8
//    on the same 4-bank span (SQ_LDS_BANK_CONFLICT = 6.29M, ~192cy/iter/blk);
//    new slot index (4ks+quad)^(lane15&7) tiles the 8 16B slots exactly evenly
//    (= b128 minimum, conflict-free); writes become ~2-way (free).

using bf16_t = __hip_bfloat16;
typedef __bf16 bf16x8 __attribute__((ext_vector_type(8)));
typedef float  f32x4  __attribute__((ext_vector_type(4)));

static constexpr int BATCH = 2;
static constexpr int NQ    = 4096;
static constexpr int NKV   = 4096;
static constexpr int NH    = 8;
static constexpr int DH    = 64;
static constexpr int INNER = NH * DH;   // 512
static constexpr int QDIM  = 1024;
static constexpr int CDIM  = 768;
// Q is pre-scaled by SCALE*log2(e) so softmax uses exp2 directly.
static constexpr float QSCALE = 0.125f * 1.4426950408889634f;  // 0.18033688

#define MFMA_BF16(a, b, c) __builtin_amdgcn_mfma_f32_16x16x32_bf16((a), (b), (c), 0, 0, 0)

__device__ __forceinline__ float fast_exp2(float x) {
  return __builtin_amdgcn_exp2f(x);
}

// async global->LDS, 16B per lane; LDS dest is wave-uniform base + lane*16 (HW).
__device__ __forceinline__ void gload16(const bf16_t* g, bf16_t* l) {
  __builtin_amdgcn_global_load_lds((__attribute__((address_space(1))) void*)(g),
                                   (__attribute__((address_space(3))) void*)(l),
                                   16, 0, 0);
}

// ---------- fused prep: f32->bf16 cast of x and ctx + 4 weight transposes ----------
// blocks [0, 7168): cast (x then ctx, 8 f32 -> 8 bf16 per thread)
// blocks [7168, 8960): 32x32 transpose tiles of Wq/Wk/Wv/Wo -> bf16 WT
__global__ __launch_bounds__(256) void prep_kernel(const float* __restrict__ x,
                                                   const float* __restrict__ ctx,
                                                   const float* __restrict__ Wq,
                                                   const float* __restrict__ Wk,
                                                   const float* __restrict__ Wv,
                                                   const float* __restrict__ Wo,
                                                   bf16_t* __restrict__ xb,
                                                   bf16_t* __restrict__ ctxb,
                                                   bf16_t* __restrict__ WqT,
                                                   bf16_t* __restrict__ WkvT,
                                                   bf16_t* __restrict__ WoT) {
  constexpr int XN8 = BATCH * NQ * QDIM / 8;   // 1048576 (4096 blocks)
  constexpr int CN8 = BATCH * NKV * CDIM / 8;  // 786432  (3072 blocks)
  constexpr int CAST_BLK = (XN8 + CN8) / 256;  // 7168
  __shared__ float tile[32][33];
  const int bid = blockIdx.x;
  if (bid < CAST_BLK) {
    int id = bid * 256 + threadIdx.x;
    const float* in;
    bf16_t* out;
    if (id < XN8) {
      in = x; out = xb;
    } else {
      id -= XN8; in = ctx; out = ctxb;
    }
    float4 a = ((const float4*)in)[2 * id];
    float4 b = ((const float4*)in)[2 * id + 1];
    bf16_t t[8] = {__float2bfloat16(a.x), __float2bfloat16(a.y), __float2bfloat16(a.z),
                   __float2bfloat16(a.w), __float2bfloat16(b.x), __float2bfloat16(b.y),
                   __float2bfloat16(b.z), __float2bfloat16(b.w)};
    ((uint4*)out)[id] = *(const uint4*)t;
    return;
  }
  int wb = bid - CAST_BLK;
  const float* W;
  bf16_t* WT;
  int K, N;
  if (wb < 512) {
    W = Wq; WT = WqT; K = QDIM; N = INNER;                            // 32x16 tiles
  } else if (wb < 896) {
    wb -= 512; W = Wk; WT = WkvT; K = CDIM; N = INNER;                // 24x16
  } else if (wb < 1280) {
    wb -= 896; W = Wv; WT = WkvT + (size_t)INNER * CDIM; K = CDIM; N = INNER;  // 24x16
  } else {
    wb -= 1280; W = Wo; WT = WoT; K = INNER; N = QDIM;                // 16x32
  }
  const int bnt = N / 32;
  const int bn = (wb % bnt) * 32, bk = (wb / bnt) * 32;
  const int tx = threadIdx.x & 31, ty = threadIdx.x >> 5;  // ty 0..7
  for (int yy = ty; yy < 32; yy += 8)
    tile[yy][tx] = W[(size_t)(bk + yy) * N + bn + tx];
  __syncthreads();
  for (int yy = ty; yy < 32; yy += 8)
    WT[(size_t)(bn + yy) * K + bk + tx] = __float2bfloat16(tile[tx][yy]);
}

// ---------- 128x128 MFMA GEMM core, triple-buffer + counted vmcnt ----------
// Per iter: wait vmcnt(4) [stage(t) done, stage(t+1) in flight]; s_barrier;
// issue stage(t+2); ds_read fragments (swizzled); 16 MFMA/wave.
// Swizzle (rule #21): LDS stays linear; the 16B column-granule of the GLOBAL
// source is XOR'd with s(row)=(row>>1)&3, and reads XOR the same way.
__device__ __forceinline__ void gemm128_core(const bf16_t* __restrict__ A,
                                             const bf16_t* __restrict__ WT, int K,
                                             int m0, int n0, int tid,
                                             f32x4 (&acc)[4][4],
                                             bf16_t (*As)[128][32],
                                             bf16_t (*Bs)[128][32]) {
  const int lane = tid & 63, wave = tid >> 6;
  const int lane15 = lane & 15, quad = lane >> 4;
  const int wm = (wave >> 1) * 64, wn = (wave & 1) * 64;
  const int srow = tid >> 2;                                // 0..63 (+64 chunk)
  const int scol = ((tid & 3) ^ ((srow >> 1) & 3)) * 8;     // inverse-swizzled src
  const bf16_t* aptr = A + (size_t)(m0 + srow) * K + scol;
  const bf16_t* bptr = WT + (size_t)(n0 + srow) * K + scol;
  bf16_t* const ab = &As[0][wave * 16][0];   // wave-uniform base (+lane*16 by HW)
  bf16_t* const bb = &Bs[0][wave * 16][0];
  constexpr int BUF = 128 * 32;

  auto stage = [&](int t) {
    const int c = (t % 3) * BUF;
    const bf16_t* as = aptr + t * 32;
    const bf16_t* bs = bptr + t * 32;
    gload16(as, ab + c);                                   // A rows [0,64)
    gload16(as + (size_t)64 * K, ab + c + 64 * 32);        // A rows [64,128)
    gload16(bs, bb + c);
    gload16(bs + (size_t)64 * K, bb + c + 64 * 32);        // B rows [64,128)
  };

  const int T = K / 32;
  stage(0);
  stage(1);
  for (int t = 0; t < T; ++t) {
    const int cur = t % 3;
    if (t < T - 1) {
      asm volatile("s_waitcnt vmcnt(4)" ::: "memory");  // buf[t] done, buf[t+1] flying
    } else {
      asm volatile("s_waitcnt vmcnt(0)" ::: "memory");  // tail
    }
    asm volatile("s_barrier" ::: "memory");
    if (t + 2 < T) stage(t + 2);                        // never drained this iter
    bf16x8 af[4], bfr[4];
#pragma unroll
    for (int i = 0; i < 4; ++i) {
      const int row = wm + i * 16 + lane15;
      af[i] = *reinterpret_cast<const bf16x8*>(
          &As[cur][0][0] + row * 32 + ((quad * 8) ^ (((row >> 1) & 3) * 8)));
    }
#pragma unroll
    for (int j = 0; j < 4; ++j) {
      const int row = wn + j * 16 + lane15;
      bfr[j] = *reinterpret_cast<const bf16x8*>(
          &Bs[cur][0][0] + row * 32 + ((quad * 8) ^ (((row >> 1) & 3) * 8)));
    }
#pragma unroll
    for (int i = 0; i < 4; ++i)
#pragma unroll
      for (int j = 0; j < 4; ++j) acc[i][j] = MFMA_BF16(af[i], bfr[j], acc[i][j]);
  }
}

// ---------- merged Q + KV projection: 768 blocks, XCD-chunked swizzle ----------
// virtual vb: bx = vb/12 (m-tile), bsel = vb%12: bsel<4 -> Q n-tile, else KV n-tile.
// XCD chunking puts all 12 bsel of 8 consecutive m-tiles on one XCD: the A
// panels (xb/ctxb rows) are fetched once per XCD instead of 4-8x.
__global__ __launch_bounds__(256, 3) void qkv_gemm_kernel(const bf16_t* __restrict__ xb,
                                                          const bf16_t* __restrict__ ctxb,
                                                          const bf16_t* __restrict__ WqT,
                                                          const bf16_t* __restrict__ WkvT,
                                                          bf16_t* __restrict__ qob,
                                                          bf16_t* __restrict__ kb,
                                                          bf16_t* __restrict__ vtb) {
  __shared__ __align__(16) bf16_t As[3][128][32];   // 24 KB
  __shared__ __align__(16) bf16_t Bs[3][128][32];   // 24 KB
  const int tid = threadIdx.x;
  const int bid = blockIdx.x;                 // 768 = 8 XCDs x 96
  const int vb = (bid & 7) * 96 + (bid >> 3); // bijective (768 % 8 == 0)
  const int bx = vb / 12, bsel = vb % 12;
  const bool isq = bsel < 4;
  const bf16_t* A  = isq ? xb : ctxb;
  const bf16_t* WT = isq ? WqT : WkvT;
  const int K  = isq ? QDIM : CDIM;
  const int m0 = bx * 128;
  const int n0 = (isq ? bsel : bsel - 4) * 128;

  const f32x4 vzero = {0.f, 0.f, 0.f, 0.f};
  f32x4 acc[4][4];
  for (int i = 0; i < 4; ++i)
    for (int j = 0; j < 4; ++j) acc[i][j] = vzero;

  gemm128_core(A, WT, K, m0, n0, tid, acc, As, Bs);

  // epilogue: C/D layout col=lane&15, row=quad*4+reg  [verified m89/m91]
  const int lane = tid & 63, wave = tid >> 6;
  const int lane15 = lane & 15, quad = lane >> 4;
  const int wm = (wave >> 1) * 64, wn = (wave & 1) * 64;
  for (int i = 0; i < 4; ++i) {
    int gm = m0 + wm + i * 16 + quad * 4;
    for (int j = 0; j < 4; ++j) {
      int gn = n0 + wn + j * 16 + lane15;
      for (int r = 0; r < 4; ++r) {
        float v = acc[i][j][r];
        if (isq) {
          qob[(size_t)(gm + r) * INNER + gn] = __float2bfloat16(v * QSCALE);
        } else if (gn < INNER) {
          kb[(size_t)(gm + r) * INNER + gn] = __float2bfloat16(v);
        } else {
          int gmr = gm + r;  // vt[b][c][mi], b = gmr/4096, mi = gmr%4096
          vtb[((size_t)(gmr >> 12) * INNER + (gn - INNER)) * (size_t)NKV +
              (gmr & 4095)] = __float2bfloat16(v);
        }
      }
    }
  }
}

// ---------- output projection: 512 blocks, XCD-chunked swizzle ----------
__global__ __launch_bounds__(256, 3) void out_gemm_kernel(const bf16_t* __restrict__ A,
                                                          const bf16_t* __restrict__ WT,
                                                          float* __restrict__ C,
                                                          const float* __restrict__ bias) {
  __shared__ __align__(16) bf16_t As[3][128][32];
  __shared__ __align__(16) bf16_t Bs[3][128][32];
  const int tid = threadIdx.x;
  const int bid = blockIdx.x;                 // 512 = 8 XCDs x 64
  const int vb = (bid & 7) * 64 + (bid >> 3); // bijective
  const int m0 = (vb >> 3) * 128, n0 = (vb & 7) * 128;  // 8 n-tiles share m-panel
  constexpr int K = INNER, N = QDIM;

  const f32x4 vzero = {0.f, 0.f, 0.f, 0.f};
  f32x4 acc[4][4];
  for (int i = 0; i < 4; ++i)
    for (int j = 0; j < 4; ++j) acc[i][j] = vzero;

  gemm128_core(A, WT, K, m0, n0, tid, acc, As, Bs);

  const int lane = tid & 63, wave = tid >> 6;
  const int lane15 = lane & 15, quad = lane >> 4;
  const int wm = (wave >> 1) * 64, wn = (wave & 1) * 64;
  float bv[4];
  for (int j = 0; j < 4; ++j) bv[j] = bias[n0 + wn + j * 16 + lane15];
  for (int i = 0; i < 4; ++i) {
    int gm = m0 + wm + i * 16 + quad * 4;
    for (int j = 0; j < 4; ++j) {
      int gn = n0 + wn + j * 16 + lane15;
      for (int r = 0; r < 4; ++r)
        C[(size_t)(gm + r) * N + gn] = acc[i][j][r] + bv[j];
    }
  }
}

// ---------- flash attention: one (b, h, 128-row Q tile) per block ----------
// 256 threads = 4 waves x 32 q-rows. Each wave reads the shared 8 KB K-tile
// and 8 KB V-tile once per iter for 2x16 output rows. S^T = K Q^T; packed b64
// Ps writes in A-operand layout (wave-private rows -> lgkmcnt fence, no second
// barrier). K/V register prefetch double-buffered; ONE barrier per tile, never
// draining the prefetch's vmcnt. l via ones-MFMA (acc_l rows == acc_o rows).
// XCD-chunked block swizzle: one XCD handles 2 (h,b) pairs -> K/V L2-local.
// PsA is XOR-swizzled (byte ^= (row&7)<<4, stride 128B): pf b128 reads tile
// the 8 16B slots exactly evenly (bank minimum); writes ~2-way (free).
__global__ __launch_bounds__(256, 2) void attn_kernel(const bf16_t* Qg /*[b][m][c]*/,
                                                      const bf16_t* __restrict__ Kg /*[b][m][c]*/,
                                                      const bf16_t* __restrict__ Vtg /*[b][c][m]*/,
                                                      bf16_t* Og /*[b][m][c], may alias Qg*/) {
  // fragment-major: chunk c = ks*4+j holds 64 lanes x 8 bf16 (16B/lane)
  __shared__ __align__(16) bf16_t KsF[2][8][512];  // 16 KB
  __shared__ __align__(16) bf16_t VtF[2][8][512];  // 16 KB
  __shared__ __align__(16) bf16_t PsA[128][64];    // 16 KB, XOR-swizzled

  const int tid = threadIdx.x;
  const int lane = tid & 63, wave = tid >> 6;     // wave 0..3
  const int lane15 = lane & 15, quad = lane >> 4;
  const int wrow = wave * 32;                     // 32 q-rows per wave
  const int bid = blockIdx.x;                     // 512 = 8 XCDs x 64
  const int vb = (bid & 7) * 64 + (bid >> 3);     // bijective (512 % 8 == 0)
  const int qt = vb & 31, hb = vb >> 5;           // qt fastest within (h,b)
  const int h = hb & 7, b = hb >> 3;
  const int q0 = qt * 128;

  const size_t qbase  = ((size_t)b * NQ + q0) * INNER + h * DH;
  const size_t kbase  = ((size_t)b * NKV) * INNER + h * DH;
  const size_t vtbase = ((size_t)(b * NH + h) * DH) * NKV;

  // Q fragments direct from global: layout m=lane15, k=quad*8+j (pre-scaled)
  bf16x8 qf[2][2];  // [ks][qh]
  for (int ks = 0; ks < 2; ++ks)
    for (int qh = 0; qh < 2; ++qh)
      qf[ks][qh] = *reinterpret_cast<const bf16x8*>(
          Qg + qbase + (size_t)(wrow + qh * 16 + lane15) * INNER + ks * 32 + quad * 8);

  bf16x8 ones;
#pragma unroll
  for (int i = 0; i < 8; ++i) ones[i] = (__bf16)1.0f;

  const f32x4 vzero = {0.f, 0.f, 0.f, 0.f};
  f32x4 acc_o[2][4];   // [qh][j]
  f32x4 acc_l[2];      // [qh]
  for (int qh = 0; qh < 2; ++qh) {
    acc_l[qh] = vzero;
    for (int j = 0; j < 4; ++j) acc_o[qh][j] = vzero;
  }

  // wave stages chunks c0 = 2*wave, c1 = 2*wave+1 of K and V; lane's 16B:
  //   K[kv = (c&3)*16+lane15][k = (c>>2)*32+quad*8 ..+7]
  //   Vt[d = (c&3)*16+lane15][kv = kv0+(c>>2)*32+quad*8 ..+7]
  const int c0 = wave * 2, c1 = wave * 2 + 1;
  auto kaddr = [&](int c, int kv0) {
    return Kg + kbase + (size_t)(kv0 + (c & 3) * 16 + lane15) * INNER + (c >> 2) * 32 + quad * 8;
  };
  auto vaddr = [&](int c, int kv0) {
    return Vtg + vtbase + (size_t)((c & 3) * 16 + lane15) * NKV + kv0 + (c >> 2) * 32 + quad * 8;
  };
  uint4 kr0 = *(const uint4*)kaddr(c0, 0), kr1 = *(const uint4*)kaddr(c1, 0);
  uint4 vr0 = *(const uint4*)vaddr(c0, 0), vr1 = *(const uint4*)vaddr(c1, 0);

  constexpr int T = NKV / 64;
  for (int t = 0; t < T; ++t) {
    const int cur = t & 1;
    *(uint4*)&KsF[cur][c0][lane * 8] = kr0;  // compiler waits vmcnt for kr/vr here
    *(uint4*)&KsF[cur][c1][lane * 8] = kr1;
    *(uint4*)&VtF[cur][c0][lane * 8] = vr0;
    *(uint4*)&VtF[cur][c1][lane * 8] = vr1;
    __syncthreads();  // publish buf[cur]; no outstanding vmcnt (kr/vr consumed)

    // prefetch next K/V tile right after the barrier: full-iter latency cover
    if (t + 1 < T) {
      const int kv0n = (t + 1) * 64;
      kr0 = *(const uint4*)kaddr(c0, kv0n);
      kr1 = *(const uint4*)kaddr(c1, kv0n);
      vr0 = *(const uint4*)vaddr(c0, kv0n);
      vr1 = *(const uint4*)vaddr(c1, kv0n);
    }

    // S^T tiles: rows = kv (A = K-frag), cols = q-row (B = Q-frag, 2x16 rows)
    f32x4 acc_st[2][4];  // [qh][j]
#pragma unroll
    for (int qh = 0; qh < 2; ++qh)
      for (int j = 0; j < 4; ++j) acc_st[qh][j] = vzero;
    __builtin_amdgcn_s_setprio(1);
#pragma unroll
    for (int ks = 0; ks < 2; ++ks) {
      bf16x8 kf[4];
#pragma unroll
      for (int j = 0; j < 4; ++j)
        kf[j] = *reinterpret_cast<const bf16x8*>(&KsF[cur][ks * 4 + j][lane * 8]);
#pragma unroll
      for (int qh = 0; qh < 2; ++qh)
#pragma unroll
        for (int j = 0; j < 4; ++j)
          acc_st[qh][j] = MFMA_BF16(kf[j], qf[ks][qh], acc_st[qh][j]);
    }
    __builtin_amdgcn_s_setprio(0);

    // softmax: p = exp2(s); lane holds kv = j*16+quad*4+r for q-row
    // wrow+qh*16+lane15 -> pack 4 kv-consecutive p as one b64 write at the
    // XOR-swizzled column (byte ^= (row&7)<<4)
#pragma unroll
    for (int qh = 0; qh < 2; ++qh)
#pragma unroll
      for (int j = 0; j < 4; ++j) {
        bf16_t t4[4];
        for (int r = 0; r < 4; ++r)
          t4[r] = __float2bfloat16(fast_exp2(acc_st[qh][j][r]));
        const int prow = wrow + qh * 16 + lane15;
        *(uint2*)((char*)PsA + prow * 128 +
                  ((j * 32 + quad * 8) ^ ((prow & 7) << 4))) = *(const uint2*)t4;
      }
    // PsA rows [wrow, wrow+32) are written and read by THIS wave only:
    // LDS-write completion fence is sufficient, and it doesn't touch vmcnt
    // (so the kr/vr prefetch is never drained here).
    asm volatile("s_waitcnt lgkmcnt(0)" ::: "memory");

    // O += P V   (A: PsA[m][kv=quad*8+jj] via swizzled read, B: VtF frag-major)
    // l += P 1   (acc_l row quad*4+r = q-row offset, replicated over lane15)
    __builtin_amdgcn_s_setprio(1);
#pragma unroll
    for (int ks = 0; ks < 2; ++ks) {
      bf16x8 vf[4];
#pragma unroll
      for (int j = 0; j < 4; ++j)
        vf[j] = *reinterpret_cast<const bf16x8*>(&VtF[cur][ks * 4 + j][lane * 8]);
#pragma unroll
      for (int qh = 0; qh < 2; ++qh) {
        const int prow = wrow + qh * 16 + lane15;
        bf16x8 pf = *reinterpret_cast<const bf16x8*>(
            (const char*)PsA + prow * 128 +
            ((ks * 64 + quad * 16) ^ ((prow & 7) << 4)));
        acc_l[qh] = MFMA_BF16(pf, ones, acc_l[qh]);
#pragma unroll
        for (int j = 0; j < 4; ++j) acc_o[qh][j] = MFMA_BF16(pf, vf[j], acc_o[qh][j]);
      }
    }
    __builtin_amdgcn_s_setprio(0);
  }

  // acc_l[qh][r] is l for q-row = wrow + qh*16 + quad*4 + r (acc_o's row slot)
  for (int qh = 0; qh < 2; ++qh)
    for (int r = 0; r < 4; ++r) {
      float invr = 1.f / acc_l[qh][r];
      int row = wrow + qh * 16 + quad * 4 + r;
      for (int j = 0; j < 4; ++j)
        Og[qbase + (size_t)row * INNER + j * 16 + lane15] =
            __float2bfloat16(acc_o[qh][j][r] * invr);
    }
}

extern "C" void kernel_launch(void* const* d_in, const int* in_sizes, int n_in,
                              void* d_out, int out_size, void* d_ws, size_t ws_size,
                              hipStream_t stream) {
  (void)in_sizes; (void)n_in; (void)out_size; (void)ws_size;
  const float* x   = (const float*)d_in[0];  // [2][4096][1024]
  const float* ctx = (const float*)d_in[1];  // [2][4096][768]
  const float* Wq  = (const float*)d_in[2];  // [1024][512]
  const float* Wk  = (const float*)d_in[3];  // [768][512]
  const float* Wv  = (const float*)d_in[4];  // [768][512]
  const float* Wo  = (const float*)d_in[5];  // [512][1024]
  const float* bo  = (const float*)d_in[6];  // [1024]
  float* out = (float*)d_out;                // [2][4096][1024], 33.5 MB

  // workspace layout (~28.8 MB)
  char* ws = (char*)d_ws;
  size_t off = 0;
  auto take = [&](size_t nelem) { bf16_t* p = (bf16_t*)(ws + off); off += nelem * 2; return p; };
  bf16_t* WqT  = take((size_t)INNER * QDIM);        // [512][1024]
  bf16_t* WkvT = take((size_t)(2 * INNER) * CDIM);  // [1024][768]: Wk^T then Wv^T
  bf16_t* WoT  = take((size_t)QDIM * INNER);        // [1024][512]
  bf16_t* qob  = take((size_t)BATCH * NQ * INNER);  // Q (pre-scaled), later O
  bf16_t* kb   = take((size_t)BATCH * NKV * INNER);
  bf16_t* vtb  = take((size_t)BATCH * INNER * NKV); // V transposed [b][c][m]

  // bf16 copies of x/ctx live in d_out (dead until the final GEMM writes it):
  // xb 16.8 MB + ctxb 12.6 MB = 29.4 MB <= 33.5 MB.
  bf16_t* xb   = (bf16_t*)d_out;
  bf16_t* ctxb = xb + (size_t)BATCH * NQ * QDIM;

  // fused cast + weight transpose: 7168 cast blocks + 1792 transpose blocks
  prep_kernel<<<8960, 256, 0, stream>>>(x, ctx, Wq, Wk, Wv, Wo, xb, ctxb, WqT, WkvT, WoT);

  // merged Q + KV projections: 768 blocks (~3/CU at 48 KB LDS), XCD-swizzled
  qkv_gemm_kernel<<<768, 256, 0, stream>>>(xb, ctxb, WqT, WkvT, qob, kb, vtb);

  // attention; O overwrites Q in place (each block reads its Q rows before
  // writing O). 512 blocks, XCD-swizzled (2 (h,b) K/V sets per XCD).
  attn_kernel<<<512, 256, 0, stream>>>(qob, kb, vtb, qob);

  // output projection + bias (fp32 out): 512 blocks, XCD-swizzled
  out_gemm_kernel<<<512, 256, 0, stream>>>(qob, WoT, out, bo);
}